// Round 11
// baseline (91.629 us; speedup 1.0000x reference)
//
#include <hip/hip_runtime.h>
#include <hip/hip_fp16.h>

// ButterflyRotation: 12 butterfly layers over rows of 4096 fp32.
// R11: radix-16 x 3 phases (4096 = 16^3). BLOCK=256, 2 rows packed as v2f
// in interleaved 32 KiB LDS, f16 {1-cos, sin} angle table (96 KiB) with
// per-layer lazy unpack + one-phase-ahead prefetch, 2 lgkm-only barriers.
//   P1: e = 16t+k                  -> layers 0-3   (x direct from global)
//   P2: e = 256(t&15)+16m+(t>>4)   -> layers 4-7   (LDS b64, at-floor banks)
//   P3: e = t+256m                 -> layers 8-11  (LDS b64; coalesced store)

#define DIM    4096
#define LAYERS 12
#define BATCH  8192
#define NANG   2048
#define BLOCK  256

typedef unsigned int u32;
typedef float v2f __attribute__((ext_vector_type(2)));

// lgkm-only barrier: global loads stay in flight across it
#define BAR() do {                                             \
    asm volatile("s_waitcnt lgkmcnt(0)" ::: "memory");         \
    __builtin_amdgcn_sched_barrier(0);                         \
    __builtin_amdgcn_s_barrier();                              \
} while (0)

// quad-level swizzle (involution: only bits 0-2 change)
__device__ __forceinline__ int swzQ(int Q) {
    return Q ^ ((Q >> 3) & 7) ^ ((Q >> 6) & 7);
}
// element -> interleaved 8B-unit slot (quad swizzle in packed space)
__device__ __forceinline__ int uslot(int e) {
    return 2 * swzQ(e >> 1) + (e & 1);
}
// butterfly sub-index for left element m at local level jj (stride 2^jj)
__device__ __forceinline__ constexpr int inner_idx(int m, int jj) {
    return ((m >> (jj + 1)) << jj) + (m & ((1 << jj) - 1));
}

// d-form packed rotation: d = 1-cos (f16-safe), s = sin.
// nl = c*xl + s*xr = fma(s,xr, fma(-d,xl,xl)); nr = c*xr - s*xl.
__device__ __forceinline__ void rot2d(v2f& xl, v2f& xr, float d, float s) {
    v2f cl = xl - d * xl;                 // fma(-d, xl, xl) = c*xl
    v2f cr = xr - d * xr;                 // c*xr
    v2f nl = cl + s * xr;
    v2f nr = cr - s * xl;
    xl = nl; xr = nr;
}

// f16-packed transposed table: u32 = {h(1-c) | h(s)<<16}.
// group = region*8 + jj*2 + (ii>>2); flat = (group*256 + t)*4 + (ii&3).
// region 0: layer jj,   thread t, angles 8t+ii            (ii=0..7)
// region 1: layer 4+jj: angles 128(t&15)+(t>>4)+16*ii
// region 2: layer 8+jj: angles t+256*ii
__global__ void __launch_bounds__(256) cs_kernel(const float* __restrict__ angles,
                                                 u32* __restrict__ TH, int n) {
    int i = blockIdx.x * blockDim.x + threadIdx.x;
    if (i >= n) return;
    float a = angles[i];
    float c = cosf(a), s = sinf(a);
    int l = i >> 11, aa = i & 2047;
    int region, jj, t, ii;
    if (l < 4)      { region = 0; jj = l;     t = aa >> 3; ii = aa & 7; }
    else if (l < 8) { region = 1; jj = l - 4; int hi = aa >> 7, r = aa & 127;
                      ii = r >> 4; t = hi + 16 * (r & 15); }
    else            { region = 2; jj = l - 8; ii = aa >> 8; t = aa & 255; }
    int group = region * 8 + jj * 2 + (ii >> 2);
    int flat = (group * 256 + t) * 4 + (ii & 3);
    u32 lo = (u32)__half_as_ushort(__float2half(1.0f - c));
    u32 hi = (u32)__half_as_ushort(__float2half(s));
    TH[flat] = lo | (hi << 16);
}

// unpack 2 uint4 -> 8 (d,s) pairs (compile-time indices after unroll)
#define UNPACK8(Ua, Ub, dd, ss) do {                                       \
    const u32 _u[8] = {Ua.x, Ua.y, Ua.z, Ua.w, Ub.x, Ub.y, Ub.z, Ub.w};    \
    _Pragma("unroll")                                                      \
    for (int a = 0; a < 8; ++a) {                                          \
        __half2 h2 = *reinterpret_cast<const __half2*>(&_u[a]);            \
        float2 f = __half22float2(h2);                                     \
        dd[a] = f.x; ss[a] = f.y;                                          \
    }                                                                      \
} while (0)

// one phase = 4 layers (local strides 1,2,4,8) on w[16], lazy per-layer unpack
#define PHASE_ROTS(U, w)                                                   \
    _Pragma("unroll")                                                      \
    for (int jj = 0; jj < 4; ++jj) {                                       \
        float dd[8], ss[8];                                                \
        UNPACK8(U[2*jj], U[2*jj+1], dd, ss);                               \
        const int st = 1 << jj;                                            \
        _Pragma("unroll")                                                  \
        for (int m = 0; m < 16; ++m) {                                     \
            if (!(m & st)) {                                               \
                rot2d(w[m], w[m + st], dd[inner_idx(m, jj)],               \
                      ss[inner_idx(m, jj)]);                               \
            }                                                              \
        }                                                                  \
    }

__global__ void __launch_bounds__(BLOCK, 4)
butterfly_kernel(const float* __restrict__ x, const uint4* __restrict__ TH4,
                 float* __restrict__ out) {
    __shared__ v2f buf[DIM];                // 32 KiB interleaved {r0[e], r1[e]}
    const int t = threadIdx.x;
    const long row0 = (long)blockIdx.x * 2;

    v2f w[16];
    uint4 U[8];

    // ===== P1: e = 16t+k, layers 0-3; x direct from global =====
    {
        const float* p0 = x + row0 * DIM + 16 * t;
        const float* p1 = p0 + DIM;
        float4 r0q[4], r1q[4];
        #pragma unroll
        for (int q = 0; q < 4; ++q) {
            r0q[q] = *(const float4*)(p0 + 4 * q);
            r1q[q] = *(const float4*)(p1 + 4 * q);
        }
        #pragma unroll
        for (int q = 0; q < 8; ++q) U[q] = TH4[q * 256 + t];
        #pragma unroll
        for (int q = 0; q < 4; ++q) {
            w[4*q+0] = v2f{r0q[q].x, r1q[q].x};
            w[4*q+1] = v2f{r0q[q].y, r1q[q].y};
            w[4*q+2] = v2f{r0q[q].z, r1q[q].z};
            w[4*q+3] = v2f{r0q[q].w, r1q[q].w};
        }
        PHASE_ROTS(U, w)
        // prefetch P2 angles; they fly across BAR
        #pragma unroll
        for (int q = 0; q < 8; ++q) U[q] = TH4[(8 + q) * 256 + t];
        // write LDS: 8 x ds_write_b128 (units 2Q', 2Q'+1; at-floor banks)
        #pragma unroll
        for (int wq = 0; wq < 8; ++wq) {
            *(float4*)(&buf[2 * swzQ(8 * t + wq)]) =
                make_float4(w[2*wq].x, w[2*wq].y, w[2*wq+1].x, w[2*wq+1].y);
        }
    }
    BAR();

    // ===== P2: e = 256*hi + 16m + lo, layers 4-7 (b64) =====
    {
        const int hi = t & 15, lo = t >> 4;
        int ps[16];
        #pragma unroll
        for (int m = 0; m < 16; ++m) {
            ps[m] = uslot((hi << 8) + (m << 4) + lo);
            w[m] = buf[ps[m]];
        }
        PHASE_ROTS(U, w)
        // prefetch P3 angles
        #pragma unroll
        for (int q = 0; q < 8; ++q) U[q] = TH4[(16 + q) * 256 + t];
        #pragma unroll
        for (int m = 0; m < 16; ++m) buf[ps[m]] = w[m];   // own slots
    }
    BAR();

    // ===== P3: e = t + 256m, layers 8-11 (b64); coalesced store =====
    {
        #pragma unroll
        for (int m = 0; m < 16; ++m) w[m] = buf[uslot(t + (m << 8))];
        PHASE_ROTS(U, w)
        float* o0 = out + row0 * DIM + t;
        float* o1 = o0 + DIM;
        #pragma unroll
        for (int m = 0; m < 16; ++m) {
            o0[m << 8] = w[m].x;
            o1[m << 8] = w[m].y;
        }
    }
}

extern "C" void kernel_launch(void* const* d_in, const int* in_sizes, int n_in,
                              void* d_out, int out_size, void* d_ws, size_t ws_size,
                              hipStream_t stream) {
    (void)in_sizes; (void)n_in; (void)out_size; (void)ws_size;
    const float* x      = (const float*)d_in[0];
    const float* angles = (const float*)d_in[1];
    float* out = (float*)d_out;

    const int n = LAYERS * NANG;                    // 24576 angles, 96 KiB table
    cs_kernel<<<(n + 255) / 256, 256, 0, stream>>>(angles, (u32*)d_ws, n);
    butterfly_kernel<<<BATCH / 2, BLOCK, 0, stream>>>(x, (const uint4*)d_ws, out);
}